// Round 1
// baseline (371.941 us; speedup 1.0000x reference)
//
#include <hip/hip_runtime.h>

// SSIM loss, fused single-pass:
//   - separable 11-tap Gaussian (outer-product window) -> horizontal conv per
//     input row staged in LDS, vertical conv from an 11-deep register ring
//   - 5 convolved quantities per pixel: mu1, mu2, E[x1^2], E[x2^2], E[x1*x2]
//   - SSIM map + clip computed in-register, block-reduced, fp64 atomic to ws
// B=32, C=3, H=W=512 fp32; zero padding (pad=5), matching lax conv semantics.

constexpr int TW   = 128;          // tile width (threads per block)
constexpr int SH   = 64;           // tile height (output rows per block)
constexpr int ROWS = SH + 10;      // input rows streamed per block = 74
constexpr int IMG  = 512;
constexpr int HALO = TW + 10;      // 138
constexpr int PLANES = 32 * 3;     // 96
constexpr double N_PIX = 25165824.0;  // 32*3*512*512

__global__ __launch_bounds__(TW, 2) void ssim_map_kernel(
    const float* __restrict__ img1, const float* __restrict__ img2,
    double* __restrict__ partial)
{
    // normalized 1D Gaussian, sigma=1.5, K=11 (matches np.exp/g.sum())
    constexpr float GW[11] = {
        0.0010283801f, 0.0075987583f, 0.0360007721f, 0.1093607008f,
        0.2130055439f, 0.2660117257f, 0.2130055439f, 0.1093607008f,
        0.0360007721f, 0.0075987583f, 0.0010283801f };

    __shared__ float s1[HALO];
    __shared__ float s2[HALO];
    __shared__ float wsum[TW / 64];

    const int tid   = threadIdx.x;
    const int x0    = blockIdx.x * TW;
    const int y0    = blockIdx.y * SH;
    const int plane = blockIdx.z;

    const float* p1 = img1 + (size_t)plane * IMG * IMG;
    const float* p2 = img2 + (size_t)plane * IMG * IMG;

    const int  gx     = x0 + tid - 5;                    // halo-load column
    const bool gx_ok  = (gx >= 0) && (gx < IMG);
    const int  gx2    = gx + TW;                         // second halo column
    const bool gx2_ok = (tid < 10) && (gx2 < IMG);       // gx2 >= 123 always

    // 11-deep register rings for the 5 horizontally-convolved quantities.
    float h1[11], h2[11], h11[11], h22[11], h12[11];

    float acc = 0.0f;

    for (int rb = 0; rb < 77; rb += 11) {
#pragma unroll
        for (int j = 0; j < 11; ++j) {
            const int r = rb + j;              // input row index in [0,74)
            if (r < ROWS) {
                const int  y    = y0 + r - 5;
                const bool y_ok = (y >= 0) && (y < IMG);

                __syncthreads();               // prev row fully consumed
                float v1 = 0.0f, v2 = 0.0f;
                if (y_ok && gx_ok) {
                    v1 = p1[(size_t)y * IMG + gx];
                    v2 = p2[(size_t)y * IMG + gx];
                }
                s1[tid] = v1; s2[tid] = v2;
                if (tid < 10) {
                    float u1 = 0.0f, u2 = 0.0f;
                    if (y_ok && gx2_ok) {
                        u1 = p1[(size_t)y * IMG + gx2];
                        u2 = p2[(size_t)y * IMG + gx2];
                    }
                    s1[tid + TW] = u1; s2[tid + TW] = u2;
                }
                __syncthreads();

                // horizontal 11-tap conv at output column x0+tid
                float a1 = 0.f, a2 = 0.f, a11 = 0.f, a22 = 0.f, a12 = 0.f;
#pragma unroll
                for (int k = 0; k < 11; ++k) {
                    const float x1 = s1[tid + k];
                    const float x2 = s2[tid + k];
                    const float t1 = GW[k] * x1;
                    const float t2 = GW[k] * x2;
                    a1 += t1;
                    a2 += t2;
                    a11 = fmaf(t1, x1, a11);
                    a22 = fmaf(t2, x2, a22);
                    a12 = fmaf(t1, x2, a12);
                }
                h1[j] = a1;  h2[j] = a2;
                h11[j] = a11; h22[j] = a22; h12[j] = a12;
            }

            if (r >= 10 && r < ROWS) {
                // vertical 11-tap conv over the register ring.
                // row (r-10+m) lives at slot (j+1+m)%11 — all static indices.
                float m1 = 0.f, m2 = 0.f, e11 = 0.f, e22 = 0.f, e12 = 0.f;
#pragma unroll
                for (int m = 0; m < 11; ++m) {
                    const int s = (j + 1 + m) % 11;
                    m1  = fmaf(GW[m], h1[s],  m1);
                    m2  = fmaf(GW[m], h2[s],  m2);
                    e11 = fmaf(GW[m], h11[s], e11);
                    e22 = fmaf(GW[m], h22[s], e22);
                    e12 = fmaf(GW[m], h12[s], e12);
                }
                const float mu11 = m1 * m1;
                const float mu22 = m2 * m2;
                const float mu12 = m1 * m2;
                const float sg1  = fmaxf(e11 - mu11, 0.0f);
                const float sg2  = fmaxf(e22 - mu22, 0.0f);
                const float sg12 = e12 - mu12;
                const float num = (2.0f * mu12 + 1e-4f) * (2.0f * sg12 + 9e-4f);
                const float den = (mu11 + mu22 + 1e-4f) * (sg1 + sg2 + 9e-4f);
                float v = num * __builtin_amdgcn_rcpf(den);   // den >= C1*C2 > 0
                v = fminf(fmaxf(v, 0.0f), 1.0f);
                acc += v;
            }
        }
    }

    // wave (64-lane) shuffle reduction, then cross-wave via LDS
#pragma unroll
    for (int off = 32; off > 0; off >>= 1)
        acc += __shfl_down(acc, off, 64);
    if ((tid & 63) == 0) wsum[tid >> 6] = acc;
    __syncthreads();
    if (tid == 0) {
        double blocksum = 0.0;
#pragma unroll
        for (int w = 0; w < TW / 64; ++w) blocksum += (double)wsum[w];
        atomicAdd(partial, blocksum);
    }
}

__global__ void ssim_finalize_kernel(const double* __restrict__ partial,
                                     float* __restrict__ out)
{
    out[0] = 1.0f - (float)(partial[0] / N_PIX);
}

extern "C" void kernel_launch(void* const* d_in, const int* in_sizes, int n_in,
                              void* d_out, int out_size, void* d_ws, size_t ws_size,
                              hipStream_t stream) {
    const float* img1 = (const float*)d_in[0];
    const float* img2 = (const float*)d_in[1];
    float* out = (float*)d_out;
    double* acc = (double*)d_ws;

    hipMemsetAsync(acc, 0, sizeof(double), stream);   // ws is re-poisoned each launch

    dim3 grid(IMG / TW, IMG / SH, PLANES);            // 4 x 8 x 96 = 3072 blocks
    ssim_map_kernel<<<grid, TW, 0, stream>>>(img1, img2, acc);
    ssim_finalize_kernel<<<1, 1, 0, stream>>>(acc, out);
}

// Round 2
// 274.829 us; speedup vs baseline: 1.3534x; 1.3534x over previous
//
#include <hip/hip_runtime.h>

// SSIM loss v2 — fused separable Gaussian SSIM, software-pipelined:
//   - 256 threads/block, each owns 2 adjacent columns -> full 512-wide rows
//     (no x-halo loads; zero padding lives in LDS pad cells, written once)
//   - triple-buffered LDS row stream, ONE barrier per input row; next row's
//     globals are prefetched into registers during current row's compute
//   - horizontal 11-tap conv reads 7 aligned ds_read_b64 per image
//   - vertical 11-tap conv from float2 register rings (static %11 indexing
//     via fully-unrolled j-loop), SSIM map in-register, block-reduce,
//     one fp64 atomicAdd per block into d_ws
// B=32, C=3, H=W=512 fp32; zero padding (pad=5) matches lax conv semantics.

constexpr int IMG    = 512;
constexpr int TPB    = 256;          // threads/block; 2 cols per thread
constexpr int SH     = 64;           // output rows per block
constexpr int ROWS   = SH + 10;      // 74 input rows streamed
constexpr int PAD    = 6;            // left pad (even -> aligned float2 ops)
constexpr int LROW   = 528;          // PAD + 512 + 6 right pad + align slack
constexpr int PLANES = 32 * 3;       // 96
constexpr double N_PIX = 25165824.0; // 32*3*512*512

__global__ __launch_bounds__(TPB, 2) void ssim_map_kernel(
    const float* __restrict__ img1, const float* __restrict__ img2,
    double* __restrict__ partial)
{
    constexpr float GW[11] = {
        0.0010283801f, 0.0075987583f, 0.0360007721f, 0.1093607008f,
        0.2130055439f, 0.2660117257f, 0.2130055439f, 0.1093607008f,
        0.0360007721f, 0.0075987583f, 0.0010283801f };

    __shared__ __align__(16) float sbuf[3][2][LROW];
    __shared__ float wsum[TPB / 64];

    const int tid   = threadIdx.x;
    const int y0    = blockIdx.x * SH;
    const int plane = blockIdx.y;

    const float* p1 = img1 + (size_t)plane * IMG * IMG;
    const float* p2 = img2 + (size_t)plane * IMG * IMG;

    // zero the x-padding cells once (cols <0 and >=512); they are never
    // overwritten by the main row writes (those cover idx PAD..PAD+511).
    if (tid < 72) {
        const int b = tid / 24, r2 = tid % 24, im = r2 / 12, k = r2 % 12;
        sbuf[b][im][(k < 6) ? k : (512 + k)] = 0.0f;   // 0..5 and 518..523
    }

    // float2 register rings, 11 deep, 5 quantities
    float2 h1[11], h2[11], h11[11], h22[11], h12[11];

    // prefetch registers for the next input row
    float2 pv1, pv2;
    {   // row 0 -> y = y0 - 5
        const int y = y0 - 5;
        if ((unsigned)y < IMG) {
            pv1 = *((const float2*)(p1 + (size_t)y * IMG) + tid);
            pv2 = *((const float2*)(p2 + (size_t)y * IMG) + tid);
        } else { pv1 = make_float2(0.f, 0.f); pv2 = make_float2(0.f, 0.f); }
    }

    float acc = 0.0f;

    for (int rb = 0; rb < 77; rb += 11) {
#pragma unroll
        for (int j = 0; j < 11; ++j) {
            const int r = rb + j;                  // input row index in [0,74)
            if (r < ROWS) {
                const int buf = r % 3;
                // stage prefetched row r into LDS (aligned float2 stores)
                *((float2*)&sbuf[buf][0][PAD] + tid) = pv1;
                *((float2*)&sbuf[buf][1][PAD] + tid) = pv2;

                // issue prefetch of row r+1 (zeros on any out-of-range)
                {
                    const int y = y0 + (r + 1) - 5;
                    if (r + 1 < ROWS && (unsigned)y < IMG) {
                        pv1 = *((const float2*)(p1 + (size_t)y * IMG) + tid);
                        pv2 = *((const float2*)(p2 + (size_t)y * IMG) + tid);
                    } else { pv1 = make_float2(0.f, 0.f); pv2 = make_float2(0.f, 0.f); }
                }

                __syncthreads();   // RAW: row r visible; triple-buffer kills WAR

                // horizontal conv: cols [2t-5 .. 2t+6] live at idx [2t+1..2t+12];
                // read aligned span idx [2t .. 2t+13] as 7 float2 per image.
                float A1[14], A2[14];
                {
                    const float2* q1 = (const float2*)&sbuf[buf][0][0] + tid;
                    const float2* q2 = (const float2*)&sbuf[buf][1][0] + tid;
#pragma unroll
                    for (int i = 0; i < 7; ++i) {
                        const float2 u = q1[i]; A1[2*i] = u.x; A1[2*i+1] = u.y;
                        const float2 v = q2[i]; A2[2*i] = v.x; A2[2*i+1] = v.y;
                    }
                }
                float a1x=0.f,a1y=0.f,a2x=0.f,a2y=0.f,a11x=0.f,a11y=0.f,
                      a22x=0.f,a22y=0.f,a12x=0.f,a12y=0.f;
#pragma unroll
                for (int k = 0; k < 11; ++k) {
                    const float g = GW[k];
                    {   const float x1 = A1[1+k], x2 = A2[1+k];
                        const float t1 = g * x1,  t2 = g * x2;
                        a1x += t1; a2x += t2;
                        a11x = fmaf(t1, x1, a11x);
                        a22x = fmaf(t2, x2, a22x);
                        a12x = fmaf(t1, x2, a12x); }
                    {   const float x1 = A1[2+k], x2 = A2[2+k];
                        const float t1 = g * x1,  t2 = g * x2;
                        a1y += t1; a2y += t2;
                        a11y = fmaf(t1, x1, a11y);
                        a22y = fmaf(t2, x2, a22y);
                        a12y = fmaf(t1, x2, a12y); }
                }
                h1[j]  = make_float2(a1x,  a1y);
                h2[j]  = make_float2(a2x,  a2y);
                h11[j] = make_float2(a11x, a11y);
                h22[j] = make_float2(a22x, a22y);
                h12[j] = make_float2(a12x, a12y);
            }

            if (r >= 10 && r < ROWS) {
                // vertical conv over the ring: row (r-10+m) is slot (j+1+m)%11
                float m1x=0.f,m1y=0.f,m2x=0.f,m2y=0.f,e11x=0.f,e11y=0.f,
                      e22x=0.f,e22y=0.f,e12x=0.f,e12y=0.f;
#pragma unroll
                for (int m = 0; m < 11; ++m) {
                    const int s = (j + 1 + m) % 11;
                    const float g = GW[m];
                    m1x  = fmaf(g, h1[s].x,  m1x);  m1y  = fmaf(g, h1[s].y,  m1y);
                    m2x  = fmaf(g, h2[s].x,  m2x);  m2y  = fmaf(g, h2[s].y,  m2y);
                    e11x = fmaf(g, h11[s].x, e11x); e11y = fmaf(g, h11[s].y, e11y);
                    e22x = fmaf(g, h22[s].x, e22x); e22y = fmaf(g, h22[s].y, e22y);
                    e12x = fmaf(g, h12[s].x, e12x); e12y = fmaf(g, h12[s].y, e12y);
                }
#pragma unroll
                for (int c = 0; c < 2; ++c) {
                    const float m1  = c ? m1y  : m1x;
                    const float m2  = c ? m2y  : m2x;
                    const float e11 = c ? e11y : e11x;
                    const float e22 = c ? e22y : e22x;
                    const float e12 = c ? e12y : e12x;
                    const float mu11 = m1 * m1;
                    const float mu22 = m2 * m2;
                    const float mu12 = m1 * m2;
                    const float sg1  = fmaxf(e11 - mu11, 0.0f);
                    const float sg2  = fmaxf(e22 - mu22, 0.0f);
                    const float sg12 = e12 - mu12;
                    const float num = (2.0f*mu12 + 1e-4f) * (2.0f*sg12 + 9e-4f);
                    const float den = (mu11 + mu22 + 1e-4f) * (sg1 + sg2 + 9e-4f);
                    float v = num * __builtin_amdgcn_rcpf(den);  // den >= C1*C2
                    v = fminf(fmaxf(v, 0.0f), 1.0f);
                    acc += v;
                }
            }
        }
    }

    // wave shuffle reduce, then cross-wave via LDS, one atomic per block
#pragma unroll
    for (int off = 32; off > 0; off >>= 1)
        acc += __shfl_down(acc, off, 64);
    if ((tid & 63) == 0) wsum[tid >> 6] = acc;
    __syncthreads();
    if (tid == 0) {
        double blocksum = 0.0;
#pragma unroll
        for (int w = 0; w < TPB / 64; ++w) blocksum += (double)wsum[w];
        atomicAdd(partial, blocksum);
    }
}

__global__ void ssim_finalize_kernel(const double* __restrict__ partial,
                                     float* __restrict__ out)
{
    out[0] = 1.0f - (float)(partial[0] / N_PIX);
}

extern "C" void kernel_launch(void* const* d_in, const int* in_sizes, int n_in,
                              void* d_out, int out_size, void* d_ws, size_t ws_size,
                              hipStream_t stream) {
    const float* img1 = (const float*)d_in[0];
    const float* img2 = (const float*)d_in[1];
    float* out = (float*)d_out;
    double* acc = (double*)d_ws;

    hipMemsetAsync(acc, 0, sizeof(double), stream);  // ws re-poisoned each launch

    dim3 grid(IMG / SH, PLANES);                     // 8 x 96 = 768 blocks
    ssim_map_kernel<<<grid, TPB, 0, stream>>>(img1, img2, acc);
    ssim_finalize_kernel<<<1, 1, 0, stream>>>(acc, out);
}

// Round 3
// 248.177 us; speedup vs baseline: 1.4987x; 1.1074x over previous
//
#include <hip/hip_runtime.h>

// SSIM loss v3 — row-pair packed-FP32 formulation:
//   - 1 column per thread, input rows streamed in PAIRS -> every hot op is a
//     v_pk_*_f32 on a {rowA,rowB} v2f with naturally register-aligned operands
//   - LDS entry = float4 {img1[rA], img1[rB], img2[rA], img2[rB]} per column:
//     horizontal 11-tap conv = 11 aligned ds_read_b128, halves are v2f operands
//   - vertical conv: 6-entry row-pair ring (60 VGPRs, vs 110 in v2 -> no AGPR
//     round-trips); per ring entry a pk-dot with constant weight pairs
//     {g[2m],g[2m+1]} / {g[2m-1],g[2m]}, lane-sum at the end. Zero shuffle movs.
//   - triple-buffered LDS, one barrier per row-PAIR (37/block), global prefetch
// B=32, C=3, H=W=512 fp32; zero padding (pad=5) matches lax conv semantics.

typedef float v2f __attribute__((ext_vector_type(2)));
typedef float v4f __attribute__((ext_vector_type(4)));

constexpr int IMG    = 512;
constexpr int TPB    = 256;          // threads/block; 1 col/thread
constexpr int SH     = 64;           // output rows per block
constexpr int NPAIR  = 37;           // input row-pairs streamed (74 rows)
constexpr int LW     = 272;          // LDS float4 entries per buffer (8 pad each side)
constexpr int PLANES = 32 * 3;      // 96
constexpr double N_PIX = 25165824.0; // 32*3*512*512

__global__ __launch_bounds__(TPB, 3) void ssim_map_kernel(
    const float* __restrict__ img1, const float* __restrict__ img2,
    double* __restrict__ partial)
{
    constexpr float GW[11] = {
        0.0010283801f, 0.0075987583f, 0.0360007721f, 0.1093607008f,
        0.2130055439f, 0.2660117257f, 0.2130055439f, 0.1093607008f,
        0.0360007721f, 0.0075987583f, 0.0010283801f };
    // GWp[k+1] = GW[k], zero-extended both sides (for edge taps of row pairs)
    constexpr float GWp[13] = {
        0.0f,
        0.0010283801f, 0.0075987583f, 0.0360007721f, 0.1093607008f,
        0.2130055439f, 0.2660117257f, 0.2130055439f, 0.1093607008f,
        0.0360007721f, 0.0075987583f, 0.0010283801f,
        0.0f };

    __shared__ v4f  sbuf[3][LW];
    __shared__ float wsum[TPB / 64];

    const int tid   = threadIdx.x;
    const int x0    = blockIdx.x * TPB;     // 0 or 256
    const int y0    = blockIdx.y * SH;
    const int plane = blockIdx.z;

    const float* p1 = img1 + (size_t)plane * IMG * IMG;
    const float* p2 = img2 + (size_t)plane * IMG * IMG;

    // staging columns: main entry L=tid -> col x0+tid-8 ; halo entry L=256+tid
    // (tid<16) -> col x0+248+tid. Out-of-range columns/rows stage 0.0f.
    const int  c   = x0 + tid - 8;
    const bool cok = (unsigned)c < (unsigned)IMG;
    const int  c2  = x0 + 248 + tid;
    const bool c2ok = (unsigned)c2 < (unsigned)IMG;   // only used when tid<16

    // 6-entry row-pair rings for the 5 horizontally-convolved quantities
    v2f rg1[6], rg2[6], rg11[6], rg22[6], rg12[6];

    v2f accv = {0.0f, 0.0f};

    // prefetch registers for the next row pair (4 main + 4 halo)
    float pa1, pb1, pa2, pb2, qa1, qb1, qa2, qb2;
    auto prefetch = [&](int i) {
        const int  rA  = y0 - 5 + 2 * i;
        const int  rB  = rA + 1;
        const bool aok = (unsigned)rA < (unsigned)IMG;
        const bool bok = (unsigned)rB < (unsigned)IMG;
        const size_t oA = (size_t)rA * IMG;
        const size_t oB = (size_t)rB * IMG;
        pa1 = (aok && cok) ? p1[oA + c] : 0.0f;
        pb1 = (bok && cok) ? p1[oB + c] : 0.0f;
        pa2 = (aok && cok) ? p2[oA + c] : 0.0f;
        pb2 = (bok && cok) ? p2[oB + c] : 0.0f;
        if (tid < 16) {
            qa1 = (aok && c2ok) ? p1[oA + c2] : 0.0f;
            qb1 = (bok && c2ok) ? p1[oB + c2] : 0.0f;
            qa2 = (aok && c2ok) ? p2[oA + c2] : 0.0f;
            qb2 = (bok && c2ok) ? p2[oB + c2] : 0.0f;
        }
    };

    prefetch(0);

    for (int ib = 0; ib < NPAIR; ib += 6) {
#pragma unroll
        for (int j = 0; j < 6; ++j) {
            const int i = ib + j;
            if (i < NPAIR) {
                // stage prefetched row pair into LDS slot j%3 (ib%3==0 always)
                sbuf[j % 3][tid] = v4f{pa1, pb1, pa2, pb2};
                if (tid < 16) sbuf[j % 3][256 + tid] = v4f{qa1, qb1, qa2, qb2};

                if (i + 1 < NPAIR) prefetch(i + 1);

                __syncthreads();   // RAW on slot j%3; triple buffer kills WAR

                // horizontal 11-tap conv for this thread's column, both rows
                v2f a1 = {0,0}, a2 = {0,0}, a11 = {0,0}, a22 = {0,0}, a12 = {0,0};
                const v4f* sp = &sbuf[j % 3][tid + 3];
#pragma unroll
                for (int k = 0; k < 11; ++k) {
                    const v4f s  = sp[k];
                    const v2f x1 = __builtin_shufflevector(s, s, 0, 1);
                    const v2f x2 = __builtin_shufflevector(s, s, 2, 3);
                    const float g = GW[k];
                    const v2f t1 = g * x1;
                    const v2f t2 = g * x2;
                    a1 += t1;
                    a2 += t2;
                    a11 = __builtin_elementwise_fma(t1, x1, a11);
                    a22 = __builtin_elementwise_fma(t2, x2, a22);
                    a12 = __builtin_elementwise_fma(t1, x2, a12);
                }
                rg1[j] = a1;  rg2[j] = a2;
                rg11[j] = a11; rg22[j] = a22; rg12[j] = a12;
            }

            if (i >= 5 && i < NPAIR) {
                // vertical conv for output rows (y0+2q, y0+2q+1), q = i-5.
                // ring entry m (input pair q+m) sits at slot (j+1+m)%6.
                // out.x taps: {g[2m], g[2m+1]} ; out.y taps: {g[2m-1], g[2m]}
                v2f sx1={0,0}, sy1={0,0}, sx2={0,0}, sy2={0,0};
                v2f sx11={0,0}, sy11={0,0}, sx22={0,0}, sy22={0,0};
                v2f sx12={0,0}, sy12={0,0};
#pragma unroll
                for (int m = 0; m < 6; ++m) {
                    const int s = (j + 1 + m) % 6;
                    const v2f wx = { GWp[2*m + 1], GWp[2*m + 2] };
                    const v2f wy = { GWp[2*m],     GWp[2*m + 1] };
                    sx1  = __builtin_elementwise_fma(wx, rg1[s],  sx1);
                    sy1  = __builtin_elementwise_fma(wy, rg1[s],  sy1);
                    sx2  = __builtin_elementwise_fma(wx, rg2[s],  sx2);
                    sy2  = __builtin_elementwise_fma(wy, rg2[s],  sy2);
                    sx11 = __builtin_elementwise_fma(wx, rg11[s], sx11);
                    sy11 = __builtin_elementwise_fma(wy, rg11[s], sy11);
                    sx22 = __builtin_elementwise_fma(wx, rg22[s], sx22);
                    sy22 = __builtin_elementwise_fma(wy, rg22[s], sy22);
                    sx12 = __builtin_elementwise_fma(wx, rg12[s], sx12);
                    sy12 = __builtin_elementwise_fma(wy, rg12[s], sy12);
                }
                // lane-sum each pk-dot -> {row r, row r+1} packed values
                const v2f m1  = { sx1.x + sx1.y,  sy1.x + sy1.y };
                const v2f m2  = { sx2.x + sx2.y,  sy2.x + sy2.y };
                const v2f e11 = { sx11.x + sx11.y, sy11.x + sy11.y };
                const v2f e22 = { sx22.x + sx22.y, sy22.x + sy22.y };
                const v2f e12 = { sx12.x + sx12.y, sy12.x + sy12.y };

                const v2f mu11 = m1 * m1;
                const v2f mu22 = m2 * m2;
                const v2f mu12 = m1 * m2;
                const v2f zero = {0.0f, 0.0f};
                const v2f one  = {1.0f, 1.0f};
                const v2f sg1  = __builtin_elementwise_max(e11 - mu11, zero);
                const v2f sg2  = __builtin_elementwise_max(e22 - mu22, zero);
                const v2f sg12 = e12 - mu12;
                const v2f num = (2.0f * mu12 + 1e-4f) * (2.0f * sg12 + 9e-4f);
                const v2f den = (mu11 + mu22 + 1e-4f) * (sg1 + sg2 + 9e-4f);
                v2f v = { num.x * __builtin_amdgcn_rcpf(den.x),
                          num.y * __builtin_amdgcn_rcpf(den.y) };
                v = __builtin_elementwise_min(__builtin_elementwise_max(v, zero), one);
                accv += v;
            }
        }
    }

    float acc = accv.x + accv.y;
#pragma unroll
    for (int off = 32; off > 0; off >>= 1)
        acc += __shfl_down(acc, off, 64);
    if ((tid & 63) == 0) wsum[tid >> 6] = acc;
    __syncthreads();
    if (tid == 0) {
        double blocksum = 0.0;
#pragma unroll
        for (int w = 0; w < TPB / 64; ++w) blocksum += (double)wsum[w];
        atomicAdd(partial, blocksum);
    }
}

__global__ void ssim_finalize_kernel(const double* __restrict__ partial,
                                     float* __restrict__ out)
{
    out[0] = 1.0f - (float)(partial[0] / N_PIX);
}

extern "C" void kernel_launch(void* const* d_in, const int* in_sizes, int n_in,
                              void* d_out, int out_size, void* d_ws, size_t ws_size,
                              hipStream_t stream) {
    const float* img1 = (const float*)d_in[0];
    const float* img2 = (const float*)d_in[1];
    float* out = (float*)d_out;
    double* acc = (double*)d_ws;

    hipMemsetAsync(acc, 0, sizeof(double), stream);  // ws re-poisoned each launch

    dim3 grid(IMG / TPB, IMG / SH, PLANES);          // 2 x 8 x 96 = 1536 blocks
    ssim_map_kernel<<<grid, TPB, 0, stream>>>(img1, img2, acc);
    ssim_finalize_kernel<<<1, 1, 0, stream>>>(acc, out);
}